// Round 1
// baseline (113.029 us; speedup 1.0000x reference)
//
#include <hip/hip_runtime.h>
#include <cstdint>
#include <cstddef>

// Problem: B=8, C=64, H=W=32 -> N=8192 nodes, K=9 neighbors, OUT=64.
// Batches: k = [1024k,1024(k+1)) for k<=6, batch 7 = [7168,8190], batch 8 = {8191}.
// Node g <-> (b = g>>10, hw = g&1023); features x[b][c][hw] (node 8191 -> b=7).
//
// R7: mean/linear commute: mean_j(x_j)@Wl^T == mean_j(x_j@Wl^T). Precompute
//  y_l = xf@Wl^T and y_r' = xf@Wr^T + b inside k_dist (64 extra W-tile blocks,
//  B-operand = [Wl^T | Wr^T], same inner loop). k_selout loses the 128-VGPR
//  weight cache + readlane matmul -> select+gather only, 1 row/wave, 2048
//  blocks, launch_bounds(256,4) (<=128 VGPR -> 16 waves/CU). Gathers hit
//  L2-resident y_l (2 MB) with 9 independent unrolled loads (no dependent
//  chain). xf copy deleted entirely.

// ---------------------------------------------------------------------------
// k_dist, dist blocks (by<64): D[i][jj] = sq[i]+sq[j]-2*dot, 128x128/block.
// W blocks (by in [64,72)): same tile GEMM, B = Wcat (128 "cols" = 64 Wl rows
// | 64 Wr rows) -> y_l[n][o], y_r'[n][o]=...+bl[o] for i-tile (by-64)*8+bx.
// LDS: [c:32][m4:33] float4 planes (pad -> conflict-free staging+frags).
// ---------------------------------------------------------------------------
__global__ __launch_bounds__(256, 2) void k_dist(const float* __restrict__ x,
                                                 const float* __restrict__ Wl,
                                                 const float* __restrict__ Wr,
                                                 const float* __restrict__ bl,
                                                 float* __restrict__ yl,
                                                 float* __restrict__ yr,
                                                 float* __restrict__ D) {
  __shared__ float4 As4[32 * 33];   // 16.9 KB
  __shared__ float4 Bs4[32 * 33];   // 16.9 KB
  __shared__ float sqA[128];
  __shared__ float sqB[128];
  int bx = blockIdx.x, by = blockIdx.y;
  bool is_w = (by >= 64);
  int i0, j0 = 0;
  if (is_w) {
    i0 = (((by - 64) << 3) + bx) << 7;          // i-tile 0..63
  } else {
    i0 = by << 7;
    int s = (i0 >= 7168) ? 7168 : (i0 & ~1023);
    j0 = s + (bx << 7);
  }
  const float* xA = x + (((size_t)(i0 >> 10)) << 16) + (i0 & 1023);
  const float* xB = is_w ? xA : x + (((size_t)(j0 >> 10)) << 16) + (j0 & 1023);
  int t = threadIdx.x;
  int tx = t & 15, ty = t >> 4;     // 16x16 thread grid

  float acc[8][8];
#pragma unroll
  for (int r = 0; r < 8; ++r)
#pragma unroll
    for (int c = 0; c < 8; ++c) acc[r][c] = 0.f;

#pragma unroll 1
  for (int pass = 0; pass < 2; ++pass) {
    if (pass) __syncthreads();      // prev-pass LDS reads done before restage
    int c0 = pass << 5;
    // stage A: u = t+256i; c = u>>5 (coalesced 128B rows), m4 = u&31
#pragma unroll
    for (int i = 0; i < 4; ++i) {
      int u = t + (i << 8);
      int c = u >> 5, m4 = u & 31;
      As4[c * 33 + m4] = *(const float4*)&xA[((size_t)(c0 + c) << 10) + (m4 << 2)];
    }
    if (!is_w) {
#pragma unroll
      for (int i = 0; i < 4; ++i) {
        int u = t + (i << 8);
        int c = u >> 5, m4 = u & 31;
        Bs4[c * 33 + m4] = *(const float4*)&xB[((size_t)(c0 + c) << 10) + (m4 << 2)];
      }
    } else {
      // stage Wcat[j][c0+c]: j<64 -> Wl row j, else Wr row j-64. Coalesced
      // 128B row reads; scalar LDS writes land on distinct banks (33c%32==c).
#pragma unroll
      for (int i = 0; i < 16; ++i) {
        int u = t + (i << 8);
        int j = u >> 5, c = u & 31;
        const float* Wsrc = (j < 64) ? Wl : Wr;
        int jr = j & 63;
        ((float*)&Bs4[c * 33 + (j >> 2)])[j & 3] = Wsrc[(jr << 6) + c0 + c];
      }
    }
    __syncthreads();
    // sq partial (dist blocks only): ascending-c fmaf chain == dot chain ->
    // d(i,i) cancels exactly.
    if (!is_w) {
      int m = t & 127;
      const float* base = (t < 128) ? (const float*)As4 : (const float*)Bs4;
      float p = 0.f;
#pragma unroll
      for (int c = 0; c < 32; ++c) {
        float v = base[(c * 33 + (m >> 2)) * 4 + (m & 3)];
        p = fmaf(v, v, p);
      }
      float* dst = (t < 128) ? sqA : sqB;
      if (pass == 0) dst[m] = p; else dst[m] += p;
    }
    // GEMM: per k, 4 ds_read_b128 frags + 64 FMA
#pragma unroll 4
    for (int k = 0; k < 32; ++k) {
      float4 a0 = As4[k * 33 + ty];        // rows 4ty..4ty+3
      float4 a1 = As4[k * 33 + 16 + ty];   // rows 64+4ty..
      float4 b0 = Bs4[k * 33 + tx];        // cols 4tx..4tx+3
      float4 b1 = Bs4[k * 33 + 16 + tx];   // cols 64+4tx..
      float av[8] = {a0.x, a0.y, a0.z, a0.w, a1.x, a1.y, a1.z, a1.w};
      float bv[8] = {b0.x, b0.y, b0.z, b0.w, b1.x, b1.y, b1.z, b1.w};
#pragma unroll
      for (int r = 0; r < 8; ++r)
#pragma unroll
        for (int c = 0; c < 8; ++c)
          acc[r][c] = fmaf(av[r], bv[c], acc[r][c]);
    }
  }
  __syncthreads();                  // sqA/sqB complete before epilogue reads

  int rloc[8];
#pragma unroll
  for (int r = 0; r < 4; ++r) { rloc[r] = (ty << 2) + r; rloc[4 + r] = 64 + (ty << 2) + r; }

  if (is_w) {
    // acc[r][0..3] = y_l[n][4tx..4tx+3]; acc[r][4..7] = y_r[n][4tx..4tx+3]
    float4 blv = *(const float4*)&bl[tx << 2];
#pragma unroll
    for (int r = 0; r < 8; ++r) {
      int n = i0 + rloc[r];
      float4 o0, o1;
      o0.x = acc[r][0]; o0.y = acc[r][1]; o0.z = acc[r][2]; o0.w = acc[r][3];
      o1.x = acc[r][4] + blv.x; o1.y = acc[r][5] + blv.y;
      o1.z = acc[r][6] + blv.z; o1.w = acc[r][7] + blv.w;
      *(float4*)&yl[((size_t)n << 6) + (tx << 2)] = o0;
      *(float4*)&yr[((size_t)n << 6) + (tx << 2)] = o1;
    }
    return;
  }

  int cloc[8];
#pragma unroll
  for (int c = 0; c < 4; ++c) { cloc[c] = (tx << 2) + c; cloc[4 + c] = 64 + (tx << 2) + c; }
  float sqi[8], sqj[8];
#pragma unroll
  for (int r = 0; r < 8; ++r) sqi[r] = sqA[rloc[r]];
#pragma unroll
  for (int c = 0; c < 8; ++c) sqj[c] = sqB[cloc[c]];
#pragma unroll
  for (int r = 0; r < 8; ++r) {
    size_t rb = ((size_t)(i0 + rloc[r]) << 10) + (bx << 7);
    float4 o0, o1;
    o0.x = sqi[r] + sqj[0] - 2.f * acc[r][0];
    o0.y = sqi[r] + sqj[1] - 2.f * acc[r][1];
    o0.z = sqi[r] + sqj[2] - 2.f * acc[r][2];
    o0.w = sqi[r] + sqj[3] - 2.f * acc[r][3];
    o1.x = sqi[r] + sqj[4] - 2.f * acc[r][4];
    o1.y = sqi[r] + sqj[5] - 2.f * acc[r][5];
    o1.z = sqi[r] + sqj[6] - 2.f * acc[r][6];
    o1.w = sqi[r] + sqj[7] - 2.f * acc[r][7];
    *(float4*)&D[rb + (tx << 2)] = o0;
    *(float4*)&D[rb + 64 + (tx << 2)] = o1;
  }
}

// ---------------------------------------------------------------------------
// k_selout: top-9 select + gather of precomputed y rows. 2048 blocks x 4
// waves, 1 row per wave. Key = (orderable-dist << 32) | jj, jj = 256q+4*lane+e
// (per-instruction contiguous 1KB float4 reads) -> unique keys, smaller-index
// tie-break (matches lax.top_k). 9 y_l gathers issued as independent loads.
// ---------------------------------------------------------------------------
__global__ __launch_bounds__(256, 4) void k_selout(const float* __restrict__ D,
                                                   const float* __restrict__ yl,
                                                   const float* __restrict__ yr,
                                                   float* __restrict__ out) {
  int t = threadIdx.x;
  int lane = t & 63;
  int w = t >> 6;
  int n = ((int)blockIdx.x << 2) + w;

  float rv = yr[((size_t)n << 6) + lane];   // issue early (bias already folded)
  float acc;
  if (n == 8191) {                          // singleton batch: self only
    acc = yl[((size_t)n << 6) + lane];
  } else {
    int s = (n >= 7168) ? 7168 : (n & ~1023);
    bool mlast = (n >= 7168);               // batch-7 rows exclude node 8191
    const float* drow = D + ((size_t)n << 10);
    unsigned long long cand[16];
#pragma unroll
    for (int q = 0; q < 4; ++q) {
      float4 v = *(const float4*)&drow[(q << 8) + (lane << 2)];
      float vv[4] = {v.x, v.y, v.z, v.w};
#pragma unroll
      for (int e = 0; e < 4; ++e) {
        unsigned u = __float_as_uint(vv[e]);
        u = (u & 0x80000000u) ? ~u : (u | 0x80000000u);
        unsigned jj = (unsigned)((q << 8) + (lane << 2) + e);
        cand[(q << 2) + e] = ((unsigned long long)u << 32) | jj;
      }
    }
    if (mlast && lane == 63) cand[15] = ~0ull;   // jj=1023 -> q=3,lane=63,e=3
    // per-lane top-2 cache
    unsigned long long m1 = cand[0], m2 = cand[1];
    if (m2 < m1) { unsigned long long tt = m1; m1 = m2; m2 = tt; }
#pragma unroll
    for (int q = 2; q < 16; ++q) {
      unsigned long long c = cand[q];
      unsigned long long lo = (c < m1) ? c : m1;
      unsigned long long hi = (c < m1) ? m1 : c;
      m2 = (hi < m2) ? hi : m2;
      m1 = lo;
    }
    unsigned long long lm = m1;
    unsigned rmask = 0;
    bool stale = false;
    unsigned j9[9];
#pragma unroll
    for (int kk = 0; kk < 9; ++kk) {
      unsigned long long g = lm;
#pragma unroll
      for (int off = 32; off; off >>= 1) {
        unsigned ghi = __shfl_xor((unsigned)(g >> 32), off, 64);
        unsigned glo = __shfl_xor((unsigned)g, off, 64);
        unsigned long long o = ((unsigned long long)ghi << 32) | glo;
        g = (o < g) ? o : g;
      }
      j9[kk] = (unsigned)s + ((unsigned)g & 1023u);
      if (lm == g) {                // exactly one winner lane (unique keys)
        // slot = (q<<2)|e reconstructed from jj bits [9:8],[1:0]
        unsigned slot = (((unsigned)g >> 6) & 12u) | ((unsigned)g & 3u);
        rmask |= 1u << slot;
        if (!stale) { lm = m2; stale = true; }
        else {                      // rare: rescan excluding removed slots
          unsigned long long best = ~0ull;
#pragma unroll
          for (int q = 0; q < 16; ++q) {
            bool alive = ((rmask >> q) & 1u) == 0u;
            unsigned long long c = cand[q];
            best = (alive && c < best) ? c : best;
          }
          lm = best;
        }
      }
    }
    // 9 independent gathers (uniform rows -> coalesced 256B), tree sum
    float g0 = yl[((size_t)j9[0] << 6) + lane];
    float g1 = yl[((size_t)j9[1] << 6) + lane];
    float g2 = yl[((size_t)j9[2] << 6) + lane];
    float g3 = yl[((size_t)j9[3] << 6) + lane];
    float g4 = yl[((size_t)j9[4] << 6) + lane];
    float g5 = yl[((size_t)j9[5] << 6) + lane];
    float g6 = yl[((size_t)j9[6] << 6) + lane];
    float g7 = yl[((size_t)j9[7] << 6) + lane];
    float g8 = yl[((size_t)j9[8] << 6) + lane];
    acc = (((g0 + g1) + (g2 + g3)) + ((g4 + g5) + (g6 + g7)) + g8) * (1.f / 9.f);
  }
  out[((size_t)n << 6) + lane] = acc + rv;
}

// ---------------------------------------------------------------------------
extern "C" void kernel_launch(void* const* d_in, const int* in_sizes, int n_in,
                              void* d_out, int out_size, void* d_ws, size_t ws_size,
                              hipStream_t stream) {
  const float* x  = (const float*)d_in[0];   // (8,64,32,32)
  const float* Wl = (const float*)d_in[1];   // (64,64)
  const float* bl = (const float*)d_in[2];   // (64,)
  const float* Wr = (const float*)d_in[3];   // (64,64)
  float* out = (float*)d_out;                // (8192,64)

  char* ws = (char*)d_ws;
  float* yl = (float*)(ws);                  // 2 MB: xf @ Wl^T
  float* yr = (float*)(ws + 2097152);        // 2 MB: xf @ Wr^T + bl
  float* D  = (float*)(ws + 4194304);        // 32 MB: distances

  k_dist<<<dim3(8, 72), 256, 0, stream>>>(x, Wl, Wr, bl, yl, yr, D);
  k_selout<<<2048, 256, 0, stream>>>(D, yl, yr, out);
}

// Round 3
// 112.528 us; speedup vs baseline: 1.0045x; 1.0045x over previous
//
#include <hip/hip_runtime.h>
#include <cstdint>
#include <cstddef>

// Problem: B=8, C=64, H=W=32 -> N=8192 nodes, K=9 neighbors, OUT=64.
// Batches: b = [1024b,1024(b+1)) for b<=6, batch 7 = [7168,8190], batch 8 = {8191}.
// Node g <-> (b = g>>10, hw = g&1023); features x[b][c][hw] (node 8191 -> b=7).
//
// R9: R8's cooperative single-kernel fusion silently no-op'd (absmax == max|ref|
//  => zeros; cooperative launch under graph capture / occupancy rejection).
//  Revert to 2 regular launches, keep the triangular-symmetry producer:
//  k_dist grid = 352 blocks: 288 triangular dist tiles (D bitwise-symmetric:
//  identical fmaf chains both orientations; off-diag tiles also write the
//  mirror tile via LDS-restaged transpose -> coalesced float4 stores) + 64
//  W tiles (y_l = xf@Wl^T, y_r' = xf@Wr^T + b; mean/linear commute).
//  352 <= 512 co-resident at 2 blocks/CU -> single occupancy round, no tail.
//  k_selout: proven R7 top-9 tournament + y-gathers, 2048 blocks x 4 waves.

// ---------------------------------------------------------------------------
__global__ __launch_bounds__(256, 2) void k_dist(const float* __restrict__ x,
                                                 const float* __restrict__ Wl,
                                                 const float* __restrict__ Wr,
                                                 const float* __restrict__ bl,
                                                 float* __restrict__ yl,
                                                 float* __restrict__ yr,
                                                 float* __restrict__ D) {
  __shared__ float4 SH[2112];          // As4[1056] | Bs4[1056]; reused as [64][132] f32 transpose buf
  float4* As4 = SH;
  float4* Bs4 = SH + 1056;
  __shared__ float sqA[128];
  __shared__ float sqB[128];
  int bi = (int)blockIdx.x;
  int t = threadIdx.x;
  int tx = t & 15, ty = t >> 4;        // 16x16 thread grid

  bool is_w = (bi >= 288);
  int i0, j0 = 0, sb = 0, ti = 0, tj = 0;
  if (is_w) {
    i0 = (bi - 288) << 7;              // i-tile 0..63
  } else {
    int b = bi / 36;                   // batch
    int rem = bi - b * 36;             // triangular: row ti has 8-ti entries
    while (rem >= 8 - ti) { rem -= (8 - ti); ++ti; }
    tj = ti + rem;
    sb = b << 10;
    i0 = sb + (ti << 7);
    j0 = sb + (tj << 7);
  }
  const float* xA = x + (((size_t)(i0 >> 10)) << 16) + (i0 & 1023);
  const float* xB = is_w ? xA : x + (((size_t)(j0 >> 10)) << 16) + (j0 & 1023);

  float acc[8][8];
#pragma unroll
  for (int r = 0; r < 8; ++r)
#pragma unroll
    for (int c = 0; c < 8; ++c) acc[r][c] = 0.f;

#pragma unroll 1
  for (int pass = 0; pass < 2; ++pass) {
    if (pass) __syncthreads();         // prev-pass LDS reads done before restage
    int c0 = pass << 5;
    // stage A: u = t+256i; c = u>>5 (coalesced 128B rows), m4 = u&31
#pragma unroll
    for (int i = 0; i < 4; ++i) {
      int u = t + (i << 8);
      int c = u >> 5, m4 = u & 31;
      As4[c * 33 + m4] = *(const float4*)&xA[((size_t)(c0 + c) << 10) + (m4 << 2)];
    }
    if (!is_w) {
#pragma unroll
      for (int i = 0; i < 4; ++i) {
        int u = t + (i << 8);
        int c = u >> 5, m4 = u & 31;
        Bs4[c * 33 + m4] = *(const float4*)&xB[((size_t)(c0 + c) << 10) + (m4 << 2)];
      }
    } else {
      // stage Wcat[j][c0+c]: j<64 -> Wl row j, else Wr row j-64
#pragma unroll
      for (int i = 0; i < 16; ++i) {
        int u = t + (i << 8);
        int j = u >> 5, c = u & 31;
        const float* Wsrc = (j < 64) ? Wl : Wr;
        int jr = j & 63;
        ((float*)&Bs4[c * 33 + (j >> 2)])[j & 3] = Wsrc[(jr << 6) + c0 + c];
      }
    }
    __syncthreads();
    // sq partial (dist blocks only): ascending-c fmaf chain == dot chain ->
    // d(i,i) cancels exactly (and mirror tiles are bitwise-equal).
    if (!is_w) {
      int m = t & 127;
      const float* base = (t < 128) ? (const float*)As4 : (const float*)Bs4;
      float p = 0.f;
#pragma unroll
      for (int c = 0; c < 32; ++c) {
        float v = base[(c * 33 + (m >> 2)) * 4 + (m & 3)];
        p = fmaf(v, v, p);
      }
      float* dst = (t < 128) ? sqA : sqB;
      if (pass == 0) dst[m] = p; else dst[m] += p;
    }
    // GEMM: per k, 4 ds_read_b128 frags + 64 FMA
#pragma unroll 4
    for (int k = 0; k < 32; ++k) {
      float4 a0 = As4[k * 33 + ty];
      float4 a1 = As4[k * 33 + 16 + ty];
      float4 b0 = Bs4[k * 33 + tx];
      float4 b1 = Bs4[k * 33 + 16 + tx];
      float av[8] = {a0.x, a0.y, a0.z, a0.w, a1.x, a1.y, a1.z, a1.w};
      float bv[8] = {b0.x, b0.y, b0.z, b0.w, b1.x, b1.y, b1.z, b1.w};
#pragma unroll
      for (int r = 0; r < 8; ++r)
#pragma unroll
        for (int c = 0; c < 8; ++c)
          acc[r][c] = fmaf(av[r], bv[c], acc[r][c]);
    }
  }
  __syncthreads();                     // GEMM LDS reads + sq writes complete

  int rloc[8];
#pragma unroll
  for (int r = 0; r < 4; ++r) { rloc[r] = (ty << 2) + r; rloc[4 + r] = 64 + (ty << 2) + r; }

  if (is_w) {
    // acc[r][0..3] = y_l[n][4tx..], acc[r][4..7] = y_r[n][4tx..]
    float4 blv = *(const float4*)&bl[tx << 2];
#pragma unroll
    for (int r = 0; r < 8; ++r) {
      int n = i0 + rloc[r];
      float4 o0, o1;
      o0.x = acc[r][0]; o0.y = acc[r][1]; o0.z = acc[r][2]; o0.w = acc[r][3];
      o1.x = acc[r][4] + blv.x; o1.y = acc[r][5] + blv.y;
      o1.z = acc[r][6] + blv.z; o1.w = acc[r][7] + blv.w;
      *(float4*)&yl[((size_t)n << 6) + (tx << 2)] = o0;
      *(float4*)&yr[((size_t)n << 6) + (tx << 2)] = o1;
    }
    return;
  }

  int cloc[8];
#pragma unroll
  for (int c = 0; c < 4; ++c) { cloc[c] = (tx << 2) + c; cloc[4 + c] = 64 + (tx << 2) + c; }
  float sqi[8], sqj[8];
#pragma unroll
  for (int r = 0; r < 8; ++r) sqi[r] = sqA[rloc[r]];
#pragma unroll
  for (int c = 0; c < 8; ++c) sqj[c] = sqB[cloc[c]];
  // fold final distance into acc
#pragma unroll
  for (int r = 0; r < 8; ++r)
#pragma unroll
    for (int c = 0; c < 8; ++c)
      acc[r][c] = sqi[r] + sqj[c] - 2.f * acc[r][c];
  // own tile: rows i0+rloc, cols (j0-sb)+cloc
#pragma unroll
  for (int r = 0; r < 8; ++r) {
    size_t rb = ((size_t)(i0 + rloc[r]) << 10) + (j0 - sb);
    float4 o0, o1;
    o0.x = acc[r][0]; o0.y = acc[r][1]; o0.z = acc[r][2]; o0.w = acc[r][3];
    o1.x = acc[r][4]; o1.y = acc[r][5]; o1.z = acc[r][6]; o1.w = acc[r][7];
    *(float4*)&D[rb + (tx << 2)] = o0;
    *(float4*)&D[rb + 64 + (tx << 2)] = o1;
  }
  if (ti != tj) {
    // mirror tile via LDS restage: half h = cols 64h..64h+63 of own tile =
    // rows j0+64h..+63 of mirror. tb is [64][132] f32 (528B rows, 16B-aligned;
    // 33792B = exactly As4|Bs4).
    float* tb = (float*)SH;
#pragma unroll 1
    for (int h = 0; h < 2; ++h) {
      __syncthreads();                 // prior LDS consumers done
#pragma unroll
      for (int r = 0; r < 8; ++r)
#pragma unroll
        for (int c = 0; c < 4; ++c)
          tb[((tx << 2) + c) * 132 + rloc[r]] = acc[r][(h << 2) + c];
      __syncthreads();
#pragma unroll
      for (int it = 0; it < 8; ++it) {
        int lin = t + (it << 8);
        int j2 = lin >> 5, u = lin & 31;
        float4 v = *(const float4*)&tb[j2 * 132 + (u << 2)];
        *(float4*)&D[((size_t)(j0 + (h << 6) + j2) << 10) + (i0 - sb) + (u << 2)] = v;
      }
    }
  }
}

// ---------------------------------------------------------------------------
// k_selout: top-9 select + gather of precomputed y rows. 2048 blocks x 4
// waves, 1 row per wave. Key = (orderable-dist << 32) | jj, jj = 256q+4*lane+e
// (per-instruction contiguous 1KB float4 reads) -> unique keys, smaller-index
// tie-break (matches lax.top_k). 9 y_l gathers issued as independent loads.
// ---------------------------------------------------------------------------
__global__ __launch_bounds__(256, 4) void k_selout(const float* __restrict__ D,
                                                   const float* __restrict__ yl,
                                                   const float* __restrict__ yr,
                                                   float* __restrict__ out) {
  int t = threadIdx.x;
  int lane = t & 63;
  int w = t >> 6;
  int n = ((int)blockIdx.x << 2) + w;

  float rv = yr[((size_t)n << 6) + lane];   // issue early (bias already folded)
  float acc;
  if (n == 8191) {                          // singleton batch: self only
    acc = yl[((size_t)n << 6) + lane];
  } else {
    int s = (n >= 7168) ? 7168 : (n & ~1023);
    bool mlast = (n >= 7168);               // batch-7 rows exclude node 8191
    const float* drow = D + ((size_t)n << 10);
    unsigned long long cand[16];
#pragma unroll
    for (int q = 0; q < 4; ++q) {
      float4 v = *(const float4*)&drow[(q << 8) + (lane << 2)];
      float vv[4] = {v.x, v.y, v.z, v.w};
#pragma unroll
      for (int e = 0; e < 4; ++e) {
        unsigned u = __float_as_uint(vv[e]);
        u = (u & 0x80000000u) ? ~u : (u | 0x80000000u);
        unsigned jj = (unsigned)((q << 8) + (lane << 2) + e);
        cand[(q << 2) + e] = ((unsigned long long)u << 32) | jj;
      }
    }
    if (mlast && lane == 63) cand[15] = ~0ull;   // jj=1023 -> q=3,lane=63,e=3
    // per-lane top-2 cache
    unsigned long long m1 = cand[0], m2 = cand[1];
    if (m2 < m1) { unsigned long long tt = m1; m1 = m2; m2 = tt; }
#pragma unroll
    for (int q = 2; q < 16; ++q) {
      unsigned long long c = cand[q];
      unsigned long long lo = (c < m1) ? c : m1;
      unsigned long long hi = (c < m1) ? m1 : c;
      m2 = (hi < m2) ? hi : m2;
      m1 = lo;
    }
    unsigned long long lm = m1;
    unsigned rmask = 0;
    bool stale = false;
    unsigned j9[9];
#pragma unroll
    for (int kk = 0; kk < 9; ++kk) {
      unsigned long long g = lm;
#pragma unroll
      for (int off = 32; off; off >>= 1) {
        unsigned ghi = __shfl_xor((unsigned)(g >> 32), off, 64);
        unsigned glo = __shfl_xor((unsigned)g, off, 64);
        unsigned long long o = ((unsigned long long)ghi << 32) | glo;
        g = (o < g) ? o : g;
      }
      j9[kk] = (unsigned)s + ((unsigned)g & 1023u);
      if (lm == g) {                // exactly one winner lane (unique keys)
        unsigned slot = (((unsigned)g >> 6) & 12u) | ((unsigned)g & 3u);
        rmask |= 1u << slot;
        if (!stale) { lm = m2; stale = true; }
        else {                      // rare: rescan excluding removed slots
          unsigned long long best = ~0ull;
#pragma unroll
          for (int q = 0; q < 16; ++q) {
            bool alive = ((rmask >> q) & 1u) == 0u;
            unsigned long long c = cand[q];
            best = (alive && c < best) ? c : best;
          }
          lm = best;
        }
      }
    }
    // 9 independent gathers (uniform rows -> coalesced 256B), tree sum
    float g0 = yl[((size_t)j9[0] << 6) + lane];
    float g1 = yl[((size_t)j9[1] << 6) + lane];
    float g2 = yl[((size_t)j9[2] << 6) + lane];
    float g3 = yl[((size_t)j9[3] << 6) + lane];
    float g4 = yl[((size_t)j9[4] << 6) + lane];
    float g5 = yl[((size_t)j9[5] << 6) + lane];
    float g6 = yl[((size_t)j9[6] << 6) + lane];
    float g7 = yl[((size_t)j9[7] << 6) + lane];
    float g8 = yl[((size_t)j9[8] << 6) + lane];
    acc = (((g0 + g1) + (g2 + g3)) + ((g4 + g5) + (g6 + g7)) + g8) * (1.f / 9.f);
  }
  out[((size_t)n << 6) + lane] = acc + rv;
}

// ---------------------------------------------------------------------------
extern "C" void kernel_launch(void* const* d_in, const int* in_sizes, int n_in,
                              void* d_out, int out_size, void* d_ws, size_t ws_size,
                              hipStream_t stream) {
  const float* x  = (const float*)d_in[0];   // (8,64,32,32)
  const float* Wl = (const float*)d_in[1];   // (64,64)
  const float* bl = (const float*)d_in[2];   // (64,)
  const float* Wr = (const float*)d_in[3];   // (64,64)
  float* out = (float*)d_out;                // (8192,64)

  char* ws = (char*)d_ws;
  float* yl = (float*)(ws);                  // 2 MB: xf @ Wl^T
  float* yr = (float*)(ws + 2097152);        // 2 MB: xf @ Wr^T + bl
  float* D  = (float*)(ws + 4194304);        // 32 MB: distances

  k_dist<<<dim3(352), 256, 0, stream>>>(x, Wl, Wr, bl, yl, yr, D);
  k_selout<<<2048, 256, 0, stream>>>(D, yl, yr, out);
}